// Round 1
// baseline (244.376 us; speedup 1.0000x reference)
//
#include <hip/hip_runtime.h>

#define B_SZ    64
#define S_LEN   448
#define D_MODEL 1024
#define N_HEAD  16
#define D_HEAD  64
#define CHUNK   28
#define NCH     16    // 16 * 28 = 448

// ---------------------------------------------------------------------------
// GEMM partial: P[(mat*8+kt)][b][n] = sum_{k in kt-range} X[b][k] * W[k][n]
// grid = (16 ntiles, 8 ktiles, nmat), block = 256
// thread: n = nt*64 + (t&63), bg = t>>6 (4 groups of 16 b), 16 accumulators
// ---------------------------------------------------------------------------
__global__ __launch_bounds__(256) void gemm_part(
    const float* __restrict__ X,
    const float* __restrict__ W0, const float* __restrict__ W1,
    const float* __restrict__ W2,
    float* __restrict__ P)
{
    const int nt  = blockIdx.x;
    const int kt  = blockIdx.y;
    const int mat = blockIdx.z;
    const float* __restrict__ W = (mat == 0) ? W0 : ((mat == 1) ? W1 : W2);

    const int t  = threadIdx.x;
    const int n  = nt * 64 + (t & 63);
    // wave-uniform b-group base; force scalar so X loads become s_load
    const int b0 = __builtin_amdgcn_readfirstlane((t >> 6) * 16);
    const int k0 = kt * 128;

    float acc[16];
#pragma unroll
    for (int j = 0; j < 16; ++j) acc[j] = 0.f;

#pragma unroll 4
    for (int k = k0; k < k0 + 128; ++k) {
        const float w = W[k * D_MODEL + n];
#pragma unroll
        for (int j = 0; j < 16; ++j)
            acc[j] += X[(b0 + j) * D_MODEL + k] * w;
    }

    float* p = P + (size_t)(mat * 8 + kt) * (B_SZ * D_MODEL);
#pragma unroll
    for (int j = 0; j < 16; ++j)
        p[(b0 + j) * D_MODEL + n] = acc[j];
}

// reduce 8 k-partials for q,k,v -> out[mat][b][n] (contiguous 3*65536)
__global__ __launch_bounds__(256) void reduce_qkv(
    const float* __restrict__ P, float* __restrict__ out)
{
    const int i   = blockIdx.x * 256 + threadIdx.x;   // < 196608
    const int mat = i >> 16;
    const int r   = i & 65535;
    float s = 0.f;
#pragma unroll
    for (int kt = 0; kt < 8; ++kt)
        s += P[(size_t)(mat * 8 + kt) * 65536 + r];
    out[i] = s;
}

// reduce 8 k-partials + bias -> final out projection
__global__ __launch_bounds__(256) void reduce_out(
    const float* __restrict__ P, const float* __restrict__ bo,
    float* __restrict__ out)
{
    const int i = blockIdx.x * 256 + threadIdx.x;     // < 65536
    float s = bo[i & (D_MODEL - 1)];
#pragma unroll
    for (int kt = 0; kt < 8; ++kt)
        s += P[(size_t)kt * 65536 + i];
    out[i] = s;
}

// ---------------------------------------------------------------------------
// Fused cache-copy + chunked attention partials.
// grid = (NCH chunks, B), block = 256. Thread t: cols 4t..4t+3, head h=t/16.
// Reads each K/V cache row exactly once: writes it to k_upd/v_upd and
// computes per-head scores / weighted-V partial (flash-decoding style).
// ---------------------------------------------------------------------------
__global__ __launch_bounds__(256) void stream_attn(
    const float* __restrict__ kcache, const float* __restrict__ vcache,
    const float* __restrict__ qws, const float* __restrict__ kws,
    const float* __restrict__ vws,
    const float* __restrict__ bq, const float* __restrict__ bv,
    const float* __restrict__ amask, const int* __restrict__ idxp,
    float* __restrict__ kout, float* __restrict__ vout,
    float* __restrict__ accws, float* __restrict__ mlws)
{
    const int c   = blockIdx.x;
    const int b   = blockIdx.y;
    const int t   = threadIdx.x;
    const int col = t * 4;
    const int h   = t >> 4;
    const int l16 = t & 15;
    const int idx = idxp[0];
    const int s0  = c * CHUNK;

    // q row (with bias); score scale (Dh^-0.25)^2 = 0.125 applied to dot
    float4 q = *(const float4*)(qws + b * D_MODEL + col);
    {
        float4 b4 = *(const float4*)(bq + col);
        q.x += b4.x; q.y += b4.y; q.z += b4.z; q.w += b4.w;
    }

    float sc[CHUNK];
#pragma unroll
    for (int s = 0; s < CHUNK; ++s) {
        const int srow = s0 + s;
        const float* kp = (srow == idx) ? (kws + b * D_MODEL)
                                        : (kcache + (size_t)(b * S_LEN + srow) * D_MODEL);
        float4 k4 = *(const float4*)(kp + col);
        *(float4*)(kout + (size_t)(b * S_LEN + srow) * D_MODEL + col) = k4;
        float p = q.x * k4.x + q.y * k4.y + q.z * k4.z + q.w * k4.w;
        p += __shfl_xor(p, 1);
        p += __shfl_xor(p, 2);
        p += __shfl_xor(p, 4);
        p += __shfl_xor(p, 8);
        sc[s] = p * 0.125f + amask[srow];
    }

    float m = sc[0];
#pragma unroll
    for (int s = 1; s < CHUNK; ++s) m = fmaxf(m, sc[s]);
    float l = 0.f;
#pragma unroll
    for (int s = 0; s < CHUNK; ++s) { sc[s] = __expf(sc[s] - m); l += sc[s]; }

    float4 bv4 = *(const float4*)(bv + col);
    float4 acc = make_float4(0.f, 0.f, 0.f, 0.f);
#pragma unroll
    for (int s = 0; s < CHUNK; ++s) {
        const int srow = s0 + s;
        const bool isn = (srow == idx);
        const float* vp = isn ? (vws + b * D_MODEL)
                              : (vcache + (size_t)(b * S_LEN + srow) * D_MODEL);
        float4 v4 = *(const float4*)(vp + col);
        if (isn) { v4.x += bv4.x; v4.y += bv4.y; v4.z += bv4.z; v4.w += bv4.w; }
        *(float4*)(vout + (size_t)(b * S_LEN + srow) * D_MODEL + col) = v4;
        acc.x += sc[s] * v4.x; acc.y += sc[s] * v4.y;
        acc.z += sc[s] * v4.z; acc.w += sc[s] * v4.w;
    }

    // store partials: acc[(b*16+h)][c][64], ml[(b*16+h)][c][2]
    float* ap = accws + ((size_t)(b * N_HEAD + h) * NCH + c) * D_HEAD + l16 * 4;
    *(float4*)ap = acc;
    if (l16 == 0) {
        const int w = (b * N_HEAD + h) * NCH + c;
        mlws[w * 2]     = m;
        mlws[w * 2 + 1] = l;
    }
}

// combine chunk partials -> wv[b][h*64+d]
__global__ __launch_bounds__(256) void combine(
    const float* __restrict__ accws, const float* __restrict__ mlws,
    float* __restrict__ wvws)
{
    const int t = threadIdx.x;
    const int w = blockIdx.x * 4 + (t >> 6);   // (b*16+h), 0..1023
    const int d = t & 63;

    float mv[NCH], lv[NCH];
    float M = -1e30f;
#pragma unroll
    for (int c = 0; c < NCH; ++c) {
        mv[c] = mlws[(w * NCH + c) * 2];
        lv[c] = mlws[(w * NCH + c) * 2 + 1];
        M = fmaxf(M, mv[c]);
    }
    float L = 0.f, O = 0.f;
#pragma unroll
    for (int c = 0; c < NCH; ++c) {
        const float f = __expf(mv[c] - M);
        L += lv[c] * f;
        O += accws[(w * NCH + c) * D_HEAD + d] * f;
    }
    const int b = w >> 4, h = w & 15;
    wvws[b * D_MODEL + h * D_HEAD + d] = O / L;
}

// ---------------------------------------------------------------------------
extern "C" void kernel_launch(void* const* d_in, const int* in_sizes, int n_in,
                              void* d_out, int out_size, void* d_ws, size_t ws_size,
                              hipStream_t stream) {
    const float* x      = (const float*)d_in[0];
    const float* kcache = (const float*)d_in[1];
    const float* vcache = (const float*)d_in[2];
    const int*   idxp   = (const int*)d_in[3];
    const float* amask  = (const float*)d_in[4];
    const float* Wq     = (const float*)d_in[5];
    const float* bq     = (const float*)d_in[6];
    const float* Wk     = (const float*)d_in[7];
    const float* Wv     = (const float*)d_in[8];
    const float* bv     = (const float*)d_in[9];
    const float* Wo     = (const float*)d_in[10];
    const float* bo     = (const float*)d_in[11];

    float* out  = (float*)d_out;                 // [64][1024]
    float* kout = out + 65536;                   // [64][448][1024]
    float* vout = kout + (size_t)B_SZ * S_LEN * D_MODEL;

    float* ws    = (float*)d_ws;
    float* qws   = ws;                 // 65536
    float* kws   = ws + 65536;         // 65536
    float* vws   = ws + 131072;        // 65536
    float* part  = ws + 196608;        // 3*8*65536 = 1572864 (reused for outproj)
    float* accws = ws + 1769472;       // 1024*16*64 = 1048576
    float* mlws  = ws + 2818048;       // 32768
    float* wvws  = ws + 2850816;       // 65536   (total ~11.7 MB)

    // q/k/v projections (k-split partials, no bias — biases folded downstream)
    gemm_part<<<dim3(16, 8, 3), 256, 0, stream>>>(x, Wq, Wk, Wv, part);
    reduce_qkv<<<768, 256, 0, stream>>>(part, qws);

    // fused cache update + attention partials
    stream_attn<<<dim3(NCH, B_SZ), 256, 0, stream>>>(
        kcache, vcache, qws, kws, vws, bq, bv, amask, idxp,
        kout, vout, accws, mlws);

    // softmax combine -> wv
    combine<<<256, 256, 0, stream>>>(accws, mlws, wvws);

    // output projection
    gemm_part<<<dim3(16, 8, 1), 256, 0, stream>>>(wvws, Wo, Wo, Wo, part);
    reduce_out<<<256, 256, 0, stream>>>(part, bo, out);
}

// Round 2
// 169.721 us; speedup vs baseline: 1.4399x; 1.4399x over previous
//
#include <hip/hip_runtime.h>

#define B_SZ    64
#define S_LEN   448
#define D_MODEL 1024
#define N_HEAD  16
#define D_HEAD  64
#define CHUNK   28
#define NCH     16    // 16 * 28 = 448

typedef float f4 __attribute__((ext_vector_type(4)));

// ---------------------------------------------------------------------------
// GEMM partial: P[(mat*8+kt)][b][n] = sum_{k in kt-range} X[b][k] * W[k][n]
// grid = (16 ntiles, 8 ktiles, nmat), block = 256
// ---------------------------------------------------------------------------
__global__ __launch_bounds__(256) void gemm_part(
    const float* __restrict__ X,
    const float* __restrict__ W0, const float* __restrict__ W1,
    const float* __restrict__ W2,
    float* __restrict__ P)
{
    const int nt  = blockIdx.x;
    const int kt  = blockIdx.y;
    const int mat = blockIdx.z;
    const float* __restrict__ W = (mat == 0) ? W0 : ((mat == 1) ? W1 : W2);

    const int t  = threadIdx.x;
    const int n  = nt * 64 + (t & 63);
    const int b0 = __builtin_amdgcn_readfirstlane((t >> 6) * 16);
    const int k0 = kt * 128;

    float acc[16];
#pragma unroll
    for (int j = 0; j < 16; ++j) acc[j] = 0.f;

#pragma unroll 8
    for (int k = k0; k < k0 + 128; ++k) {
        const float w = W[k * D_MODEL + n];
#pragma unroll
        for (int j = 0; j < 16; ++j)
            acc[j] += X[(b0 + j) * D_MODEL + k] * w;
    }

    float* p = P + (size_t)(mat * 8 + kt) * (B_SZ * D_MODEL);
#pragma unroll
    for (int j = 0; j < 16; ++j)
        p[(b0 + j) * D_MODEL + n] = acc[j];
}

// reduce 8 k-partials for q,k,v -> out[mat][b][n] (contiguous 3*65536)
__global__ __launch_bounds__(256) void reduce_qkv(
    const float* __restrict__ P, float* __restrict__ out)
{
    const int i   = blockIdx.x * 256 + threadIdx.x;   // < 196608
    const int mat = i >> 16;
    const int r   = i & 65535;
    float s = 0.f;
#pragma unroll
    for (int kt = 0; kt < 8; ++kt)
        s += P[(size_t)(mat * 8 + kt) * 65536 + r];
    out[i] = s;
}

// reduce 8 k-partials + bias -> final out projection
__global__ __launch_bounds__(256) void reduce_out(
    const float* __restrict__ P, const float* __restrict__ bo,
    float* __restrict__ out)
{
    const int i = blockIdx.x * 256 + threadIdx.x;     // < 65536
    float s = bo[i & (D_MODEL - 1)];
#pragma unroll
    for (int kt = 0; kt < 8; ++kt)
        s += P[(size_t)kt * 65536 + i];
    out[i] = s;
}

// ---------------------------------------------------------------------------
// Fused cache-copy + chunked attention partials, single-pass online softmax.
// grid = (NCH, B), block = 256. Thread t: cols 4t..4t+3, head h = t>>4.
// Per row: load K+V row, nt-store both to k_upd/v_upd, 16-lane dot reduce,
// online m/l/acc update. No score array -> no spill, no runtime indexing.
// ---------------------------------------------------------------------------
__global__ __launch_bounds__(256) void stream_attn(
    const float* __restrict__ kcache, const float* __restrict__ vcache,
    const float* __restrict__ qws, const float* __restrict__ kws,
    const float* __restrict__ vws,
    const float* __restrict__ bq, const float* __restrict__ bv,
    const float* __restrict__ amask, const int* __restrict__ idxp,
    float* __restrict__ kout, float* __restrict__ vout,
    float* __restrict__ accws, float* __restrict__ mlws)
{
    const int c   = blockIdx.x;
    const int b   = blockIdx.y;
    const int t   = threadIdx.x;
    const int col = t * 4;
    const int h   = t >> 4;
    const int l16 = t & 15;
    const int idx = idxp[0];
    const int s0  = c * CHUNK;

    // q row (with bias); score scale (Dh^-0.25)^2 = 0.125 applied to dot
    f4 q = *(const f4*)(qws + b * D_MODEL + col);
    q += *(const f4*)(bq + col);
    const f4 bv4 = *(const f4*)(bv + col);

    float m = -1e30f, l = 0.f;
    f4 acc = (f4)0.f;

#pragma unroll 4
    for (int s = 0; s < CHUNK; ++s) {
        const int srow = s0 + s;
        const bool isn = (srow == idx);
        const size_t roff = (size_t)(b * S_LEN + srow) * D_MODEL + col;
        const float* kp = isn ? (kws + b * D_MODEL + col) : (kcache + roff);
        const float* vp = isn ? (vws + b * D_MODEL + col) : (vcache + roff);
        f4 k4 = *(const f4*)kp;
        f4 v4 = *(const f4*)vp;
        if (isn) v4 += bv4;
        __builtin_nontemporal_store(k4, (f4*)(kout + roff));
        __builtin_nontemporal_store(v4, (f4*)(vout + roff));

        float p = q.x * k4.x + q.y * k4.y + q.z * k4.z + q.w * k4.w;
        p += __shfl_xor(p, 1);
        p += __shfl_xor(p, 2);
        p += __shfl_xor(p, 4);
        p += __shfl_xor(p, 8);
        p = p * 0.125f + amask[srow];

        const float mn = fmaxf(m, p);
        const float f  = __expf(m - mn);   // 1.0 when max unchanged
        const float w  = __expf(p - mn);
        l = l * f + w;
        acc.x = acc.x * f + w * v4.x;
        acc.y = acc.y * f + w * v4.y;
        acc.z = acc.z * f + w * v4.z;
        acc.w = acc.w * f + w * v4.w;
        m = mn;
    }

    // store partials: acc[(b*16+h)][c][64], ml[(b*16+h)][c][2]
    float* ap = accws + ((size_t)(b * N_HEAD + h) * NCH + c) * D_HEAD + l16 * 4;
    *(f4*)ap = acc;
    if (l16 == 0) {
        const int w = (b * N_HEAD + h) * NCH + c;
        mlws[w * 2]     = m;
        mlws[w * 2 + 1] = l;
    }
}

// combine chunk partials -> wv[b][h*64+d]
__global__ __launch_bounds__(256) void combine(
    const float* __restrict__ accws, const float* __restrict__ mlws,
    float* __restrict__ wvws)
{
    const int t = threadIdx.x;
    const int w = blockIdx.x * 4 + (t >> 6);   // (b*16+h), 0..1023
    const int d = t & 63;

    float M = -1e30f;
#pragma unroll
    for (int c = 0; c < NCH; ++c)
        M = fmaxf(M, mlws[(w * NCH + c) * 2]);
    float L = 0.f, O = 0.f;
#pragma unroll
    for (int c = 0; c < NCH; ++c) {
        const float f = __expf(mlws[(w * NCH + c) * 2] - M);
        L += mlws[(w * NCH + c) * 2 + 1] * f;
        O += accws[(w * NCH + c) * D_HEAD + d] * f;
    }
    const int b = w >> 4, h = w & 15;
    wvws[b * D_MODEL + h * D_HEAD + d] = O / L;
}

// ---------------------------------------------------------------------------
extern "C" void kernel_launch(void* const* d_in, const int* in_sizes, int n_in,
                              void* d_out, int out_size, void* d_ws, size_t ws_size,
                              hipStream_t stream) {
    const float* x      = (const float*)d_in[0];
    const float* kcache = (const float*)d_in[1];
    const float* vcache = (const float*)d_in[2];
    const int*   idxp   = (const int*)d_in[3];
    const float* amask  = (const float*)d_in[4];
    const float* Wq     = (const float*)d_in[5];
    const float* bq     = (const float*)d_in[6];
    const float* Wk     = (const float*)d_in[7];
    const float* Wv     = (const float*)d_in[8];
    const float* bv     = (const float*)d_in[9];
    const float* Wo     = (const float*)d_in[10];
    const float* bo     = (const float*)d_in[11];

    float* out  = (float*)d_out;                 // [64][1024]
    float* kout = out + 65536;                   // [64][448][1024]
    float* vout = kout + (size_t)B_SZ * S_LEN * D_MODEL;

    float* ws    = (float*)d_ws;
    float* qws   = ws;                 // 65536
    float* kws   = ws + 65536;         // 65536
    float* vws   = ws + 131072;        // 65536
    float* part  = ws + 196608;        // 3*8*65536 = 1572864 (reused for outproj)
    float* accws = ws + 1769472;       // 1024*16*64 = 1048576
    float* mlws  = ws + 2818048;       // 32768
    float* wvws  = ws + 2850816;       // 65536   (total ~11.7 MB)

    // q/k/v projections (k-split partials, biases folded downstream)
    gemm_part<<<dim3(16, 8, 3), 256, 0, stream>>>(x, Wq, Wk, Wv, part);
    reduce_qkv<<<768, 256, 0, stream>>>(part, qws);

    // fused cache update + attention partials (single pass, online softmax)
    stream_attn<<<dim3(NCH, B_SZ), 256, 0, stream>>>(
        kcache, vcache, qws, kws, vws, bq, bv, amask, idxp,
        kout, vout, accws, mlws);

    // softmax combine -> wv
    combine<<<256, 256, 0, stream>>>(accws, mlws, wvws);

    // output projection
    gemm_part<<<dim3(16, 8, 1), 256, 0, stream>>>(wvws, Wo, Wo, Wo, part);
    reduce_out<<<256, 256, 0, stream>>>(part, bo, out);
}

// Round 3
// 160.201 us; speedup vs baseline: 1.5254x; 1.0594x over previous
//
#include <hip/hip_runtime.h>

#define B_SZ    64
#define S_LEN   448
#define D_MODEL 1024
#define N_HEAD  16
#define D_HEAD  64
#define CHUNK   28
#define NCH     16    // 16 * 28 = 448
#define PF      8     // prefetch depth (rows)

typedef float f4 __attribute__((ext_vector_type(4)));

// ---------------------------------------------------------------------------
// GEMM partial: P[(mat*8+kt)][b][n] = sum_{k in kt-range} X[b][k] * W[k][n]
// grid = (16 ntiles, 8 ktiles, nmat), block = 256
// ---------------------------------------------------------------------------
__global__ __launch_bounds__(256) void gemm_part(
    const float* __restrict__ X,
    const float* __restrict__ W0, const float* __restrict__ W1,
    const float* __restrict__ W2,
    float* __restrict__ P)
{
    const int nt  = blockIdx.x;
    const int kt  = blockIdx.y;
    const int mat = blockIdx.z;
    const float* __restrict__ W = (mat == 0) ? W0 : ((mat == 1) ? W1 : W2);

    const int t  = threadIdx.x;
    const int n  = nt * 64 + (t & 63);
    const int b0 = __builtin_amdgcn_readfirstlane((t >> 6) * 16);
    const int k0 = kt * 128;

    float acc[16];
#pragma unroll
    for (int j = 0; j < 16; ++j) acc[j] = 0.f;

#pragma unroll 8
    for (int k = k0; k < k0 + 128; ++k) {
        const float w = W[k * D_MODEL + n];
#pragma unroll
        for (int j = 0; j < 16; ++j)
            acc[j] += X[(b0 + j) * D_MODEL + k] * w;
    }

    float* p = P + (size_t)(mat * 8 + kt) * (B_SZ * D_MODEL);
#pragma unroll
    for (int j = 0; j < 16; ++j)
        p[(b0 + j) * D_MODEL + n] = acc[j];
}

// reduce 8 k-partials + bias -> final out projection
__global__ __launch_bounds__(256) void reduce_out(
    const float* __restrict__ P, const float* __restrict__ bo,
    float* __restrict__ out)
{
    const int i = blockIdx.x * 256 + threadIdx.x;     // < 65536
    float s = bo[i & (D_MODEL - 1)];
#pragma unroll
    for (int kt = 0; kt < 8; ++kt)
        s += P[(size_t)kt * 65536 + i];
    out[i] = s;
}

// ---------------------------------------------------------------------------
// Fused cache-copy + chunked attention partials, online softmax, 8-row
// register prefetch pipeline (16KB/wave in flight).
// grid = (NCH, B), block = 256. Thread t: cols 4t..4t+3, head h = t>>4.
// Reads q (and k_new/v_new if this chunk owns idx) directly from the k-split
// GEMM partials (L2-hot) — reduce_qkv eliminated.
// ---------------------------------------------------------------------------
__global__ __launch_bounds__(256) void stream_attn(
    const float* __restrict__ kcache, const float* __restrict__ vcache,
    const float* __restrict__ part,   // [24][64][1024]: q 0-7, k 8-15, v 16-23
    const float* __restrict__ bq, const float* __restrict__ bv,
    const float* __restrict__ amask, const int* __restrict__ idxp,
    float* __restrict__ kout, float* __restrict__ vout,
    float* __restrict__ accws, float* __restrict__ mlws)
{
    const int c   = blockIdx.x;
    const int b   = blockIdx.y;
    const int t   = threadIdx.x;
    const int col = t * 4;
    const int h   = t >> 4;
    const int l16 = t & 15;
    const int idx = idxp[0];
    const int s0  = c * CHUNK;

    // q = sum of 8 k-split partials + bias (scale 0.125 applied to score)
    f4 q = *(const f4*)(bq + col);
#pragma unroll
    for (int kt = 0; kt < 8; ++kt)
        q += *(const f4*)(part + (size_t)kt * 65536 + b * D_MODEL + col);

    // new-token k/v rows, only for the chunk that owns idx
    f4 knew = (f4)0.f, vnew = (f4)0.f;
    const bool hasidx = (idx >= s0) && (idx < s0 + CHUNK);
    if (hasidx) {
#pragma unroll
        for (int kt = 0; kt < 8; ++kt) {
            knew += *(const f4*)(part + (size_t)(8 + kt)  * 65536 + b * D_MODEL + col);
            vnew += *(const f4*)(part + (size_t)(16 + kt) * 65536 + b * D_MODEL + col);
        }
        vnew += *(const f4*)(bv + col);
    }

    const size_t base = (size_t)(b * S_LEN + s0) * D_MODEL + col;

    // prime the 8-row prefetch pipeline (16 loads in flight)
    f4 kb[PF], vb[PF];
#pragma unroll
    for (int r = 0; r < PF; ++r) {
        kb[r] = *(const f4*)(kcache + base + (size_t)r * D_MODEL);
        vb[r] = *(const f4*)(vcache + base + (size_t)r * D_MODEL);
    }

    float m = -1e30f, l = 0.f;
    f4 acc = (f4)0.f;

#pragma unroll
    for (int s = 0; s < CHUNK; ++s) {
        f4 k4 = kb[s & (PF - 1)];
        f4 v4 = vb[s & (PF - 1)];
        if (s + PF < CHUNK) {   // steady-state prefetch
            kb[s & (PF - 1)] = *(const f4*)(kcache + base + (size_t)(s + PF) * D_MODEL);
            vb[s & (PF - 1)] = *(const f4*)(vcache + base + (size_t)(s + PF) * D_MODEL);
        }
        const int srow = s0 + s;
        if (srow == idx) { k4 = knew; v4 = vnew; }
        const size_t roff = base + (size_t)s * D_MODEL;
        __builtin_nontemporal_store(k4, (f4*)(kout + roff));
        __builtin_nontemporal_store(v4, (f4*)(vout + roff));

        float p = q.x * k4.x + q.y * k4.y + q.z * k4.z + q.w * k4.w;
        p += __shfl_xor(p, 1);
        p += __shfl_xor(p, 2);
        p += __shfl_xor(p, 4);
        p += __shfl_xor(p, 8);
        p = p * 0.125f + amask[srow];

        const float mn = fmaxf(m, p);
        const float f  = __expf(m - mn);   // 1.0 when max unchanged
        const float w  = __expf(p - mn);
        l = l * f + w;
        acc.x = acc.x * f + w * v4.x;
        acc.y = acc.y * f + w * v4.y;
        acc.z = acc.z * f + w * v4.z;
        acc.w = acc.w * f + w * v4.w;
        m = mn;
    }

    // store partials: acc[(b*16+h)][c][64], ml[(b*16+h)][c][2]
    float* ap = accws + ((size_t)(b * N_HEAD + h) * NCH + c) * D_HEAD + l16 * 4;
    *(f4*)ap = acc;
    if (l16 == 0) {
        const int w = (b * N_HEAD + h) * NCH + c;
        mlws[w * 2]     = m;
        mlws[w * 2 + 1] = l;
    }
}

// combine chunk partials -> wv[b][h*64+d]
__global__ __launch_bounds__(256) void combine(
    const float* __restrict__ accws, const float* __restrict__ mlws,
    float* __restrict__ wvws)
{
    const int t = threadIdx.x;
    const int w = blockIdx.x * 4 + (t >> 6);   // (b*16+h), 0..1023
    const int d = t & 63;

    float M = -1e30f;
#pragma unroll
    for (int c = 0; c < NCH; ++c)
        M = fmaxf(M, mlws[(w * NCH + c) * 2]);
    float L = 0.f, O = 0.f;
#pragma unroll
    for (int c = 0; c < NCH; ++c) {
        const float f = __expf(mlws[(w * NCH + c) * 2] - M);
        L += mlws[(w * NCH + c) * 2 + 1] * f;
        O += accws[(w * NCH + c) * D_HEAD + d] * f;
    }
    const int b = w >> 4, h = w & 15;
    wvws[b * D_MODEL + h * D_HEAD + d] = O / L;
}

// ---------------------------------------------------------------------------
extern "C" void kernel_launch(void* const* d_in, const int* in_sizes, int n_in,
                              void* d_out, int out_size, void* d_ws, size_t ws_size,
                              hipStream_t stream) {
    const float* x      = (const float*)d_in[0];
    const float* kcache = (const float*)d_in[1];
    const float* vcache = (const float*)d_in[2];
    const int*   idxp   = (const int*)d_in[3];
    const float* amask  = (const float*)d_in[4];
    const float* Wq     = (const float*)d_in[5];
    const float* bq     = (const float*)d_in[6];
    const float* Wk     = (const float*)d_in[7];
    const float* Wv     = (const float*)d_in[8];
    const float* bv     = (const float*)d_in[9];
    const float* Wo     = (const float*)d_in[10];
    const float* bo     = (const float*)d_in[11];

    float* out  = (float*)d_out;                 // [64][1024]
    float* kout = out + 65536;                   // [64][448][1024]
    float* vout = kout + (size_t)B_SZ * S_LEN * D_MODEL;

    float* ws    = (float*)d_ws;
    float* part  = ws;                 // 24*65536 = 1572864 (reused for outproj)
    float* accws = ws + 1572864;       // 1024*16*64 = 1048576
    float* mlws  = ws + 2621440;       // 32768
    float* wvws  = ws + 2654208;       // 65536   (total ~10.9 MB)

    // q/k/v projections (k-split partials; biases folded downstream)
    gemm_part<<<dim3(16, 8, 3), 256, 0, stream>>>(x, Wq, Wk, Wv, part);

    // fused cache update + attention partials (reads partials directly)
    stream_attn<<<dim3(NCH, B_SZ), 256, 0, stream>>>(
        kcache, vcache, part, bq, bv, amask, idxp,
        kout, vout, accws, mlws);

    // softmax combine -> wv
    combine<<<256, 256, 0, stream>>>(accws, mlws, wvws);

    // output projection
    gemm_part<<<dim3(16, 8, 1), 256, 0, stream>>>(wvws, Wo, Wo, Wo, part);
    reduce_out<<<256, 256, 0, stream>>>(part, bo, out);
}